// Round 1
// baseline (57.941 us; speedup 1.0000x reference)
//
#include <hip/hip_runtime.h>
#include <hip/hip_bf16.h>
#include <stdint.h>

#define NROWS 4096
#define CDIM  512
#define TOPK  5
#define BM    128
#define BK    32

typedef __bf16 bf16x8 __attribute__((ext_vector_type(8)));
typedef float  f32x4  __attribute__((ext_vector_type(4)));

// ---------------- kernel 1: top-5 index-set keys ----------------
// One wave per row. Stable-argsort semantics: max value wins, ties -> smaller index.
__global__ void topk_keys_kernel(const float* __restrict__ feat1,
                                 unsigned long long* __restrict__ keys) {
  const int row = blockIdx.x;
  const int l   = threadIdx.x;  // 0..63
  const float* r = feat1 + (size_t)row * CDIM;
  float v[8];
  const float4 a = *(const float4*)(r + l * 8);
  const float4 b = *(const float4*)(r + l * 8 + 4);
  v[0]=a.x; v[1]=a.y; v[2]=a.z; v[3]=a.w;
  v[4]=b.x; v[5]=b.y; v[6]=b.z; v[7]=b.w;

  int sel[TOPK];
#pragma unroll
  for (int s = 0; s < TOPK; ++s) {
    float bv = -__builtin_inff();
    int   bi = 0x7fffffff;
#pragma unroll
    for (int t = 0; t < 8; ++t) {
      if (v[t] > bv) { bv = v[t]; bi = l * 8 + t; }  // strict > keeps smallest idx
    }
#pragma unroll
    for (int off = 32; off > 0; off >>= 1) {
      float ov = __shfl_xor(bv, off);
      int   oi = __shfl_xor(bi, off);
      if (ov > bv || (ov == bv && oi < bi)) { bv = ov; bi = oi; }
    }
    sel[s] = bi;                      // broadcast: all lanes agree
    const int loc = bi - l * 8;
    if (loc >= 0 && loc < 8) v[loc] = -__builtin_inff();
  }

  // sort 5 ascending (Knuth 9-comparator network)
#define CSWAP(x, y) { int mn = min(sel[x], sel[y]); int mx = max(sel[x], sel[y]); sel[x] = mn; sel[y] = mx; }
  CSWAP(0,1) CSWAP(3,4) CSWAP(2,4) CSWAP(2,3) CSWAP(1,4)
  CSWAP(0,3) CSWAP(0,2) CSWAP(1,3) CSWAP(1,2)
#undef CSWAP

  if (l == 0) {
    unsigned long long key =
        (unsigned long long)sel[0]
      | ((unsigned long long)sel[1] << 9)
      | ((unsigned long long)sel[2] << 18)
      | ((unsigned long long)sel[3] << 27)
      | ((unsigned long long)sel[4] << 36);
    keys[row] = key;
  }
}

// ---------------- kernel 2: fused GEMM + BCE epilogue ----------------
// P[j,i] = dot(prob2[j], prob1[i]); block (bi,bj) owns a 128x128 tile.
// 256 threads = 4 waves in 2x2; each wave a 64x64 sub-tile (4x4 MFMA frags).
__global__ void gemm_loss_kernel(const float* __restrict__ prob1,
                                 const float* __restrict__ prob2,
                                 const unsigned long long* __restrict__ keys,
                                 float* __restrict__ partials) {
  __shared__ __bf16 As[BM * BK];  // prob2 rows (output row j)
  __shared__ __bf16 Bs[BM * BK];  // prob1 rows (output col i)
  __shared__ float  red[256];

  const int tid = threadIdx.x;
  const int bi = blockIdx.x, bj = blockIdx.y;
  const int ib = bi * BM, jb = bj * BM;

  const int l  = tid & 63, w = tid >> 6;
  const int wr = w >> 1,  wc = w & 1;
  const int lr = l & 15,  kq = l >> 4;

  f32x4 acc[4][4] = {};
  float4 pa[2][2], pb[2][2];  // prefetch regs: 2 chunks x 8 floats per operand

  // chunk c (0..511): row = c>>2, k-slot s = c&3 (8 bf16 per slot).
  // LDS slot-swizzle: physical slot = s ^ (row & 3)  (both sides, involution)
  auto issue = [&](int k0) {
#pragma unroll
    for (int it = 0; it < 2; ++it) {
      const int c   = it * 256 + tid;
      const int row = c >> 2;
      const int kc  = (c & 3) << 3;
      const float* ga = prob2 + (size_t)(jb + row) * CDIM + k0 + kc;
      pa[it][0] = *(const float4*)ga;
      pa[it][1] = *(const float4*)(ga + 4);
      const float* gb = prob1 + (size_t)(ib + row) * CDIM + k0 + kc;
      pb[it][0] = *(const float4*)gb;
      pb[it][1] = *(const float4*)(gb + 4);
    }
  };
  auto commit = [&]() {
#pragma unroll
    for (int it = 0; it < 2; ++it) {
      const int c    = it * 256 + tid;
      const int row  = c >> 2;
      const int s    = c & 3;
      const int slot = s ^ (row & 3);
      bf16x8 va, vb;
      va[0]=(__bf16)pa[it][0].x; va[1]=(__bf16)pa[it][0].y;
      va[2]=(__bf16)pa[it][0].z; va[3]=(__bf16)pa[it][0].w;
      va[4]=(__bf16)pa[it][1].x; va[5]=(__bf16)pa[it][1].y;
      va[6]=(__bf16)pa[it][1].z; va[7]=(__bf16)pa[it][1].w;
      vb[0]=(__bf16)pb[it][0].x; vb[1]=(__bf16)pb[it][0].y;
      vb[2]=(__bf16)pb[it][0].z; vb[3]=(__bf16)pb[it][0].w;
      vb[4]=(__bf16)pb[it][1].x; vb[5]=(__bf16)pb[it][1].y;
      vb[6]=(__bf16)pb[it][1].z; vb[7]=(__bf16)pb[it][1].w;
      *(bf16x8*)&As[row * BK + slot * 8] = va;
      *(bf16x8*)&Bs[row * BK + slot * 8] = vb;
    }
  };

  issue(0);
  for (int k0 = 0; k0 < CDIM; k0 += BK) {
    __syncthreads();            // previous compute done reading LDS
    commit();
    if (k0 + BK < CDIM) issue(k0 + BK);  // overlap next loads with compute
    __syncthreads();            // LDS writes visible

    bf16x8 af[4], bfr[4];
#pragma unroll
    for (int m = 0; m < 4; ++m) {
      const int arow = wr * 64 + m * 16 + lr;
      const int slot = kq ^ (arow & 3);
      af[m] = *(const bf16x8*)&As[arow * BK + slot * 8];
    }
#pragma unroll
    for (int n = 0; n < 4; ++n) {
      const int brow = wc * 64 + n * 16 + lr;
      const int slot = kq ^ (brow & 3);
      bfr[n] = *(const bf16x8*)&Bs[brow * BK + slot * 8];
    }
#pragma unroll
    for (int m = 0; m < 4; ++m)
#pragma unroll
      for (int n = 0; n < 4; ++n)
        acc[m][n] = __builtin_amdgcn_mfma_f32_16x16x32_bf16(af[m], bfr[n], acc[m][n], 0, 0, 0);
  }

  // ---- epilogue: BCE terms. C/D layout: col = l&15, row = (l>>4)*4 + reg ----
  unsigned long long kj[16], ki[4];
#pragma unroll
  for (int m = 0; m < 4; ++m)
#pragma unroll
    for (int r = 0; r < 4; ++r)
      kj[m * 4 + r] = keys[jb + wr * 64 + m * 16 + kq * 4 + r];
#pragma unroll
  for (int n = 0; n < 4; ++n)
    ki[n] = keys[ib + wc * 64 + n * 16 + lr];

  float sum = 0.f;
#pragma unroll
  for (int m = 0; m < 4; ++m)
#pragma unroll
    for (int n = 0; n < 4; ++n)
#pragma unroll
      for (int r = 0; r < 4; ++r) {
        const float p = acc[m][n][r];
        const bool  t = (kj[m * 4 + r] == ki[n]);
        const float x = t ? p : (1.0f - p);
        sum += fmaxf(__logf(x), -100.0f);   // matches clip(log(.), -100)
      }

  red[tid] = sum;
  __syncthreads();
  for (int s = 128; s > 0; s >>= 1) {
    if (tid < s) red[tid] += red[tid + s];
    __syncthreads();
  }
  if (tid == 0) partials[blockIdx.y * gridDim.x + blockIdx.x] = red[0];
}

// ---------------- kernel 3: deterministic finalize ----------------
__global__ void finalize_kernel(const float* __restrict__ partials,
                                float* __restrict__ out) {
  __shared__ float red[256];
  float s = 0.f;
  for (int i = threadIdx.x; i < 1024; i += 256) s += partials[i];
  red[threadIdx.x] = s;
  __syncthreads();
  for (int st = 128; st > 0; st >>= 1) {
    if (threadIdx.x < st) red[threadIdx.x] += red[threadIdx.x + st];
    __syncthreads();
  }
  if (threadIdx.x == 0) out[0] = -red[0] * (1.0f / 16777216.0f);  // -mean over N^2
}

extern "C" void kernel_launch(void* const* d_in, const int* in_sizes, int n_in,
                              void* d_out, int out_size, void* d_ws, size_t ws_size,
                              hipStream_t stream) {
  (void)in_sizes; (void)n_in; (void)out_size; (void)ws_size;
  const float* feat1 = (const float*)d_in[0];
  // d_in[1] = feat2 (unused by the reference)
  const float* prob1 = (const float*)d_in[2];
  const float* prob2 = (const float*)d_in[3];
  // d_in[4] = topk scalar (fixed at 5)

  unsigned long long* keys = (unsigned long long*)d_ws;
  float* partials = (float*)((char*)d_ws + NROWS * sizeof(unsigned long long));

  topk_keys_kernel<<<NROWS, 64, 0, stream>>>(feat1, keys);
  gemm_loss_kernel<<<dim3(32, 32), 256, 0, stream>>>(prob1, prob2, keys, partials);
  finalize_kernel<<<1, 256, 0, stream>>>(partials, (float*)d_out);
}

// Round 2
// 50.049 us; speedup vs baseline: 1.1577x; 1.1577x over previous
//
#include <hip/hip_runtime.h>
#include <hip/hip_bf16.h>
#include <stdint.h>

#define NROWS 4096
#define CDIM  512
#define TOPK  5
#define BM    128
#define BK    32

typedef __bf16 bf16x8 __attribute__((ext_vector_type(8)));
typedef float  f32x4  __attribute__((ext_vector_type(4)));

// ---------------- kernel 0: f32 -> bf16 convert with slot pre-swizzle ----------------
// Global bf16 layout: within each row's 32-elem chunk, 16B slot s is stored at
// position s ^ ((row>>1)&3). A linear global_load_lds copy then yields a
// swizzled LDS tile; fragment reads XOR the same swizzle (involution).
__global__ void convert_kernel(const float* __restrict__ p1,
                               const float* __restrict__ p2,
                               __bf16* __restrict__ o1,
                               __bf16* __restrict__ o2) {
  const int t = blockIdx.x * 256 + threadIdx.x;   // 0..524287, 8 elems each
  const float* src;
  __bf16* dst;
  int e = t;
  if (t >= 262144) { src = p2; dst = o2; e = t - 262144; }
  else             { src = p1; dst = o1; }
  const int row   = e >> 6;       // 64 8-elem slots per 512-col row
  const int k8    = e & 63;
  const int chunk = k8 >> 2;      // 32-elem chunk
  const int slot  = k8 & 3;
  const int dslot = slot ^ ((row >> 1) & 3);
  const float4 a = *(const float4*)(src + (size_t)row * CDIM + k8 * 8);
  const float4 b = *(const float4*)(src + (size_t)row * CDIM + k8 * 8 + 4);
  bf16x8 v;
  v[0]=(__bf16)a.x; v[1]=(__bf16)a.y; v[2]=(__bf16)a.z; v[3]=(__bf16)a.w;
  v[4]=(__bf16)b.x; v[5]=(__bf16)b.y; v[6]=(__bf16)b.z; v[7]=(__bf16)b.w;
  *(bf16x8*)(dst + (size_t)row * CDIM + chunk * 32 + dslot * 8) = v;
}

// ---------------- kernel 1: top-5 index-set keys ----------------
__global__ void topk_keys_kernel(const float* __restrict__ feat1,
                                 unsigned long long* __restrict__ keys) {
  const int row = blockIdx.x;
  const int l   = threadIdx.x;  // 0..63
  const float* r = feat1 + (size_t)row * CDIM;
  float v[8];
  const float4 a = *(const float4*)(r + l * 8);
  const float4 b = *(const float4*)(r + l * 8 + 4);
  v[0]=a.x; v[1]=a.y; v[2]=a.z; v[3]=a.w;
  v[4]=b.x; v[5]=b.y; v[6]=b.z; v[7]=b.w;

  int sel[TOPK];
#pragma unroll
  for (int s = 0; s < TOPK; ++s) {
    float bv = -__builtin_inff();
    int   bi = 0x7fffffff;
#pragma unroll
    for (int t = 0; t < 8; ++t) {
      if (v[t] > bv) { bv = v[t]; bi = l * 8 + t; }
    }
#pragma unroll
    for (int off = 32; off > 0; off >>= 1) {
      float ov = __shfl_xor(bv, off);
      int   oi = __shfl_xor(bi, off);
      if (ov > bv || (ov == bv && oi < bi)) { bv = ov; bi = oi; }
    }
    sel[s] = bi;
    const int loc = bi - l * 8;
    if (loc >= 0 && loc < 8) v[loc] = -__builtin_inff();
  }

#define CSWAP(x, y) { int mn = min(sel[x], sel[y]); int mx = max(sel[x], sel[y]); sel[x] = mn; sel[y] = mx; }
  CSWAP(0,1) CSWAP(3,4) CSWAP(2,4) CSWAP(2,3) CSWAP(1,4)
  CSWAP(0,3) CSWAP(0,2) CSWAP(1,3) CSWAP(1,2)
#undef CSWAP

  if (l == 0) {
    unsigned long long key =
        (unsigned long long)sel[0]
      | ((unsigned long long)sel[1] << 9)
      | ((unsigned long long)sel[2] << 18)
      | ((unsigned long long)sel[3] << 27)
      | ((unsigned long long)sel[4] << 36);
    keys[row] = key;
  }
}

// ---------------- kernel 2: fused GEMM + BCE epilogue ----------------
// P[j,i] = dot(prob2[j], prob1[i]). 128x128 tile, BK=32, 4 waves (2x2),
// double-buffered LDS, one barrier per K-step, global_load_lds width-16 staging.
__global__ __launch_bounds__(256) void
gemm_loss_kernel(const __bf16* __restrict__ p1b,   // prob1 bf16 (pre-swizzled)
                 const __bf16* __restrict__ p2b,   // prob2 bf16 (pre-swizzled)
                 const unsigned long long* __restrict__ keys,
                 float* __restrict__ partials) {
  // [buf][A(4096) | B(4096)] elements; A tile = 128x32 bf16 = 8 KiB
  __shared__ __bf16 sm[2][2 * BM * BK];
  __shared__ float  red[256];

  const int tid = threadIdx.x;
  const int bi = blockIdx.x, bj = blockIdx.y;
  const int ib = bi * BM, jb = bj * BM;

  const int l  = tid & 63, w = tid >> 6;
  const int wr = w >> 1,  wc = w & 1;
  const int lr = l & 15,  kq = l >> 4;

  f32x4 acc[4][4] = {};

  // stage one 128x32 A-tile + B-tile into sm[buf] via global_load_lds (linear dest)
  auto stage = [&](int buf, int k0) {
#pragma unroll
    for (int i = 0; i < 2; ++i) {
      const int c    = (w * 2 + i) * 64 + l;   // 0..511 (16B units)
      const int row  = c >> 2;
      const int slot = c & 3;
      const __bf16* gA = p2b + (size_t)(jb + row) * CDIM + k0 + slot * 8;
      const __bf16* gB = p1b + (size_t)(ib + row) * CDIM + k0 + slot * 8;
      // wave-uniform LDS base (depends only on w,i,buf); HW adds lane*16
      __bf16* lA = &sm[buf][(w * 2 + i) * 512];
      __bf16* lB = &sm[buf][BM * BK + (w * 2 + i) * 512];
      __builtin_amdgcn_global_load_lds(
          (const __attribute__((address_space(1))) unsigned int*)(const void*)gA,
          (__attribute__((address_space(3))) unsigned int*)(void*)lA, 16, 0, 0);
      __builtin_amdgcn_global_load_lds(
          (const __attribute__((address_space(1))) unsigned int*)(const void*)gB,
          (__attribute__((address_space(3))) unsigned int*)(void*)lB, 16, 0, 0);
    }
  };

  stage(0, 0);
  __syncthreads();   // drains vmcnt -> buf0 ready

  int cur = 0;
  for (int k0 = 0; k0 < CDIM; k0 += BK) {
    if (k0 + BK < CDIM) stage(cur ^ 1, k0 + BK);   // loads in flight over compute

    bf16x8 af[4], bfr[4];
#pragma unroll
    for (int m = 0; m < 4; ++m) {
      const int arow = wr * 64 + m * 16 + lr;
      const int ps   = kq ^ ((arow >> 1) & 3);
      af[m] = *(const bf16x8*)&sm[cur][arow * BK + ps * 8];
    }
#pragma unroll
    for (int n = 0; n < 4; ++n) {
      const int brow = wc * 64 + n * 16 + lr;
      const int ps   = kq ^ ((brow >> 1) & 3);
      bfr[n] = *(const bf16x8*)&sm[cur][BM * BK + brow * BK + ps * 8];
    }
#pragma unroll
    for (int m = 0; m < 4; ++m)
#pragma unroll
      for (int n = 0; n < 4; ++n)
        acc[m][n] = __builtin_amdgcn_mfma_f32_16x16x32_bf16(af[m], bfr[n], acc[m][n], 0, 0, 0);

    __syncthreads();   // next buffer staged + this buffer free
    cur ^= 1;
  }

  // ---- epilogue: BCE terms. C/D layout: col = l&15, row = (l>>4)*4 + reg ----
  unsigned long long kj[16], ki[4];
#pragma unroll
  for (int m = 0; m < 4; ++m)
#pragma unroll
    for (int r = 0; r < 4; ++r)
      kj[m * 4 + r] = keys[jb + wr * 64 + m * 16 + kq * 4 + r];
#pragma unroll
  for (int n = 0; n < 4; ++n)
    ki[n] = keys[ib + wc * 64 + n * 16 + lr];

  float sum = 0.f;
#pragma unroll
  for (int m = 0; m < 4; ++m)
#pragma unroll
    for (int n = 0; n < 4; ++n)
#pragma unroll
      for (int r = 0; r < 4; ++r) {
        const float p = acc[m][n][r];
        const bool  t = (kj[m * 4 + r] == ki[n]);
        const float x = t ? p : (1.0f - p);
        sum += fmaxf(__logf(x), -100.0f);
      }

  red[tid] = sum;
  __syncthreads();
  for (int s = 128; s > 0; s >>= 1) {
    if (tid < s) red[tid] += red[tid + s];
    __syncthreads();
  }
  if (tid == 0) partials[blockIdx.y * gridDim.x + blockIdx.x] = red[0];
}

// ---------------- kernel 3: deterministic finalize ----------------
__global__ void finalize_kernel(const float* __restrict__ partials,
                                float* __restrict__ out) {
  __shared__ float red[256];
  float s = 0.f;
  for (int i = threadIdx.x; i < 1024; i += 256) s += partials[i];
  red[threadIdx.x] = s;
  __syncthreads();
  for (int st = 128; st > 0; st >>= 1) {
    if (threadIdx.x < st) red[threadIdx.x] += red[threadIdx.x + st];
    __syncthreads();
  }
  if (threadIdx.x == 0) out[0] = -red[0] * (1.0f / 16777216.0f);
}

extern "C" void kernel_launch(void* const* d_in, const int* in_sizes, int n_in,
                              void* d_out, int out_size, void* d_ws, size_t ws_size,
                              hipStream_t stream) {
  (void)in_sizes; (void)n_in; (void)out_size; (void)ws_size;
  const float* feat1 = (const float*)d_in[0];
  const float* prob1 = (const float*)d_in[2];
  const float* prob2 = (const float*)d_in[3];

  // ws layout: o1 bf16 (4MB) | o2 bf16 (4MB) | keys (32KB) | partials (4KB)
  __bf16* o1 = (__bf16*)d_ws;
  __bf16* o2 = (__bf16*)((char*)d_ws + (size_t)NROWS * CDIM * 2);
  unsigned long long* keys = (unsigned long long*)((char*)d_ws + (size_t)NROWS * CDIM * 4);
  float* partials = (float*)((char*)d_ws + (size_t)NROWS * CDIM * 4 + NROWS * 8);

  convert_kernel<<<2048, 256, 0, stream>>>(prob1, prob2, o1, o2);
  topk_keys_kernel<<<NROWS, 64, 0, stream>>>(feat1, keys);
  gemm_loss_kernel<<<dim3(32, 32), 256, 0, stream>>>(o1, o2, keys, partials);
  finalize_kernel<<<1, 256, 0, stream>>>(partials, (float*)d_out);
}

// Round 3
// 45.375 us; speedup vs baseline: 1.2769x; 1.1030x over previous
//
#include <hip/hip_runtime.h>
#include <hip/hip_bf16.h>
#include <stdint.h>

#define NROWS 4096
#define CDIM  512
#define TOPK  5
#define BM    256   // tile M = N
#define BK    32    // K-unit
#define NKT   16    // CDIM / BK

typedef __bf16 bf16x8 __attribute__((ext_vector_type(8)));
typedef float  f32x4  __attribute__((ext_vector_type(4)));

// ---------------- kernel 0: f32 -> bf16 convert with slot pre-swizzle ----------------
// Within each row's 32-elem K-chunk (4 slots of 8 bf16), logical slot s is stored
// at physical slot s ^ (row & 3). Linear global_load_lds staging then yields an
// LDS tile whose fragment reads (slot = kq ^ (row&3)) are bank-conflict-free.
__global__ void convert_kernel(const float* __restrict__ p1,
                               const float* __restrict__ p2,
                               __bf16* __restrict__ o1,
                               __bf16* __restrict__ o2) {
  const int t = blockIdx.x * 256 + threadIdx.x;   // 0..524287, 8 elems each
  const float* src;
  __bf16* dst;
  int e = t;
  if (t >= 262144) { src = p2; dst = o2; e = t - 262144; }
  else             { src = p1; dst = o1; }
  const int row   = e >> 6;       // 64 8-elem groups per 512-col row
  const int k8    = e & 63;
  const int chunk = k8 >> 2;      // 32-elem K-chunk
  const int slot  = k8 & 3;
  const int dslot = slot ^ (row & 3);
  const float4 a = *(const float4*)(src + (size_t)row * CDIM + k8 * 8);
  const float4 b = *(const float4*)(src + (size_t)row * CDIM + k8 * 8 + 4);
  bf16x8 v;
  v[0]=(__bf16)a.x; v[1]=(__bf16)a.y; v[2]=(__bf16)a.z; v[3]=(__bf16)a.w;
  v[4]=(__bf16)b.x; v[5]=(__bf16)b.y; v[6]=(__bf16)b.z; v[7]=(__bf16)b.w;
  *(bf16x8*)(dst + (size_t)row * CDIM + chunk * 32 + dslot * 8) = v;
}

// ---------------- kernel 1: top-5 index-set keys ----------------
__global__ void topk_keys_kernel(const float* __restrict__ feat1,
                                 unsigned long long* __restrict__ keys) {
  const int row = blockIdx.x;
  const int l   = threadIdx.x;  // 0..63
  const float* r = feat1 + (size_t)row * CDIM;
  float v[8];
  const float4 a = *(const float4*)(r + l * 8);
  const float4 b = *(const float4*)(r + l * 8 + 4);
  v[0]=a.x; v[1]=a.y; v[2]=a.z; v[3]=a.w;
  v[4]=b.x; v[5]=b.y; v[6]=b.z; v[7]=b.w;

  int sel[TOPK];
#pragma unroll
  for (int s = 0; s < TOPK; ++s) {
    float bv = -__builtin_inff();
    int   bi = 0x7fffffff;
#pragma unroll
    for (int t = 0; t < 8; ++t) {
      if (v[t] > bv) { bv = v[t]; bi = l * 8 + t; }
    }
#pragma unroll
    for (int off = 32; off > 0; off >>= 1) {
      float ov = __shfl_xor(bv, off);
      int   oi = __shfl_xor(bi, off);
      if (ov > bv || (ov == bv && oi < bi)) { bv = ov; bi = oi; }
    }
    sel[s] = bi;
    const int loc = bi - l * 8;
    if (loc >= 0 && loc < 8) v[loc] = -__builtin_inff();
  }

#define CSWAP(x, y) { int mn = min(sel[x], sel[y]); int mx = max(sel[x], sel[y]); sel[x] = mn; sel[y] = mx; }
  CSWAP(0,1) CSWAP(3,4) CSWAP(2,4) CSWAP(2,3) CSWAP(1,4)
  CSWAP(0,3) CSWAP(0,2) CSWAP(1,3) CSWAP(1,2)
#undef CSWAP

  if (l == 0) {
    unsigned long long key =
        (unsigned long long)sel[0]
      | ((unsigned long long)sel[1] << 9)
      | ((unsigned long long)sel[2] << 18)
      | ((unsigned long long)sel[3] << 27)
      | ((unsigned long long)sel[4] << 36);
    keys[row] = key;
  }
}

// ---------------- kernel 2: fused GEMM + BCE, 256^2 tile, deep pipeline ----------------
// P[j,i] = dot(prob2[j], prob1[i]). 512 threads = 8 waves (2 j-groups x 4 i-groups),
// per-wave 128x64 output = acc[8][4]. 4-slot rotating LDS K-tile buffer, staged
// 2 K-tiles ahead via global_load_lds; counted s_waitcnt vmcnt + raw s_barrier.
__global__ __launch_bounds__(512, 2) void
gemm_loss_kernel(const __bf16* __restrict__ p1b,   // prob1 bf16 (pre-swizzled), i/cols
                 const __bf16* __restrict__ p2b,   // prob2 bf16 (pre-swizzled), j/rows
                 const unsigned long long* __restrict__ keys,
                 float* __restrict__ partials) {
  // [slot][A=0/B=1][256 rows * 32 cols] bf16 = 4*2*16KB = 128 KiB
  __shared__ __bf16 sm[4][2][BM * BK];
  __shared__ float  red[512];

  const int tid = threadIdx.x;
  const int l   = tid & 63, w = tid >> 6;      // lane, wave 0..7
  const int wr  = w >> 2,  wc = w & 3;         // wave j-group (0..1), i-group (0..3)
  const int lr  = l & 15,  kq = l >> 4;

  // XCD-chunked block swizzle: xcd = bid%8 gets a 4x8 (i,j)-tile region -> ~3MB/L2
  const int bid = blockIdx.x;
  const int x   = bid & 7, wv = bid >> 3;
  const int it  = (x & 3) * 4 + (wv & 3);
  const int jt  = (x >> 2) * 8 + (wv >> 2);
  const int ib  = it * BM, jb = jt * BM;

  f32x4 acc[8][4] = {};

  // stage K-tile kt into LDS slot: 1024 16B-chunks, 2 per thread per operand
  auto stage = [&](int slot, int kt) {
    const int k0 = kt * BK;
#pragma unroll
    for (int i = 0; i < 2; ++i) {
      const int c   = i * 512 + tid;   // chunk id = row*4 + phys_slot
      const int row = c >> 2;
      const int ps  = c & 3;
      const __bf16* gA = p2b + (size_t)(jb + row) * CDIM + k0 + ps * 8;
      const __bf16* gB = p1b + (size_t)(ib + row) * CDIM + k0 + ps * 8;
      // wave-uniform LDS base (chunk (i*512 + w*64)), HW adds lane*16
      __bf16* lA = &sm[slot][0][(i * 512 + w * 64) * 8];
      __bf16* lB = &sm[slot][1][(i * 512 + w * 64) * 8];
      __builtin_amdgcn_global_load_lds(
          (const __attribute__((address_space(1))) unsigned int*)(const void*)gA,
          (__attribute__((address_space(3))) unsigned int*)(void*)lA, 16, 0, 0);
      __builtin_amdgcn_global_load_lds(
          (const __attribute__((address_space(1))) unsigned int*)(const void*)gB,
          (__attribute__((address_space(3))) unsigned int*)(void*)lB, 16, 0, 0);
    }
  };

  // compute one K-unit from LDS slot: 12 ds_read_b128 + 32 MFMA
  auto compute = [&](int slot) {
    bf16x8 af[8], bfr[4];
#pragma unroll
    for (int n = 0; n < 4; ++n) {
      const int r  = wc * 64 + n * 16 + lr;
      const int ps = kq ^ (r & 3);
      bfr[n] = *(const bf16x8*)&sm[slot][1][r * 32 + ps * 8];
    }
#pragma unroll
    for (int m = 0; m < 8; ++m) {
      const int r  = wr * 128 + m * 16 + lr;
      const int ps = kq ^ (r & 3);
      af[m] = *(const bf16x8*)&sm[slot][0][r * 32 + ps * 8];
    }
    __builtin_amdgcn_s_setprio(1);
#pragma unroll
    for (int m = 0; m < 8; ++m)
#pragma unroll
      for (int n = 0; n < 4; ++n)
        acc[m][n] = __builtin_amdgcn_mfma_f32_16x16x32_bf16(af[m], bfr[n], acc[m][n], 0, 0, 0);
    __builtin_amdgcn_s_setprio(0);
  };

  // prologue: 2 K-tiles in flight
  stage(0, 0);
  stage(1, 1);

  for (int kt = 0; kt < NKT - 2; ++kt) {
    stage((kt + 2) & 3, kt + 2);                       // keep 3 tiles in flight
    asm volatile("s_waitcnt vmcnt(8)" ::: "memory");   // own kt-loads landed
    __builtin_amdgcn_s_barrier();                      // everyone's kt-loads landed
    __builtin_amdgcn_sched_barrier(0);
    compute(kt & 3);
  }
  // kt = NKT-2: nothing left to stage
  asm volatile("s_waitcnt vmcnt(4)" ::: "memory");
  __builtin_amdgcn_s_barrier();
  __builtin_amdgcn_sched_barrier(0);
  compute((NKT - 2) & 3);
  // kt = NKT-1
  asm volatile("s_waitcnt vmcnt(0)" ::: "memory");
  __builtin_amdgcn_s_barrier();
  __builtin_amdgcn_sched_barrier(0);
  compute((NKT - 1) & 3);

  // ---- epilogue: BCE terms. C/D: col = lane&15, row = (lane>>4)*4 + reg ----
  unsigned long long kj[32], ki[4];
#pragma unroll
  for (int m = 0; m < 8; ++m)
#pragma unroll
    for (int r = 0; r < 4; ++r)
      kj[m * 4 + r] = keys[jb + wr * 128 + m * 16 + kq * 4 + r];
#pragma unroll
  for (int n = 0; n < 4; ++n)
    ki[n] = keys[ib + wc * 64 + n * 16 + lr];

  float sum = 0.f;
#pragma unroll
  for (int m = 0; m < 8; ++m)
#pragma unroll
    for (int n = 0; n < 4; ++n)
#pragma unroll
      for (int r = 0; r < 4; ++r) {
        const float p = acc[m][n][r];
        const bool  t = (kj[m * 4 + r] == ki[n]);
        const float xx = t ? p : (1.0f - p);
        sum += fmaxf(__logf(xx), -100.0f);
      }

  red[tid] = sum;
  __syncthreads();
#pragma unroll
  for (int s = 256; s > 0; s >>= 1) {
    if (tid < s) red[tid] += red[tid + s];
    __syncthreads();
  }
  if (tid == 0) partials[bid] = red[0];
}

// ---------------- kernel 3: deterministic finalize ----------------
__global__ void finalize_kernel(const float* __restrict__ partials,
                                float* __restrict__ out) {
  __shared__ float red[256];
  red[threadIdx.x] = partials[threadIdx.x];
  __syncthreads();
  for (int st = 128; st > 0; st >>= 1) {
    if (threadIdx.x < st) red[threadIdx.x] += red[threadIdx.x + st];
    __syncthreads();
  }
  if (threadIdx.x == 0) out[0] = -red[0] * (1.0f / 16777216.0f);
}

extern "C" void kernel_launch(void* const* d_in, const int* in_sizes, int n_in,
                              void* d_out, int out_size, void* d_ws, size_t ws_size,
                              hipStream_t stream) {
  (void)in_sizes; (void)n_in; (void)out_size; (void)ws_size;
  const float* feat1 = (const float*)d_in[0];
  const float* prob1 = (const float*)d_in[2];
  const float* prob2 = (const float*)d_in[3];

  // ws layout: o1 bf16 (4MB) | o2 bf16 (4MB) | keys (32KB) | partials (1KB)
  __bf16* o1 = (__bf16*)d_ws;
  __bf16* o2 = (__bf16*)((char*)d_ws + (size_t)NROWS * CDIM * 2);
  unsigned long long* keys = (unsigned long long*)((char*)d_ws + (size_t)NROWS * CDIM * 4);
  float* partials = (float*)((char*)d_ws + (size_t)NROWS * CDIM * 4 + NROWS * 8);

  convert_kernel<<<2048, 256, 0, stream>>>(prob1, prob2, o1, o2);
  topk_keys_kernel<<<NROWS, 64, 0, stream>>>(feat1, keys);
  gemm_loss_kernel<<<256, 512, 0, stream>>>(o1, o2, keys, partials);
  finalize_kernel<<<1, 256, 0, stream>>>(partials, (float*)d_out);
}

// Round 4
// 40.135 us; speedup vs baseline: 1.4437x; 1.1306x over previous
//
#include <hip/hip_runtime.h>
#include <hip/hip_bf16.h>
#include <stdint.h>

#define NROWS 4096
#define CDIM  512
#define TOPK  5
#define BMJ   128   // prob2 (j) rows per block
#define BNI   256   // prob1 (i) rows per block
#define BK    32
#define NKT   16    // CDIM / BK

typedef __bf16 bf16x8 __attribute__((ext_vector_type(8)));
typedef float  f32x4  __attribute__((ext_vector_type(4)));
typedef unsigned long long u64;

// ---------------- kernel A: prep = bf16 convert (K-tiled + swizzled) + top-5 keys ----
// bf16 layout: o[kt][row][32] with 16B slot s at physical s ^ (row&3).
// Makes GEMM staging fully contiguous and LDS reads bank-conflict-free.
__global__ __launch_bounds__(256) void
prep_kernel(const float* __restrict__ p1, const float* __restrict__ p2,
            const float* __restrict__ feat1,
            __bf16* __restrict__ o1, __bf16* __restrict__ o2,
            u64* __restrict__ keys) {
  const int bid = blockIdx.x, tid = threadIdx.x;
  if (bid < 2048) {
    // ---- convert: 4 consecutive threads read one full 128B f32 line (row, kt) ----
    const int arr = bid >> 10;            // 0: p1->o1, 1: p2->o2
    const int b2  = bid & 1023;
    const int kt  = b2 >> 6;
    const int c   = (b2 & 63) * 256 + tid;  // 0..16383 (row*4 + slot)
    const int row = c >> 2;
    const int s   = c & 3;
    const float* src = (arr ? p2 : p1) + (size_t)row * CDIM + kt * 32 + s * 8;
    __bf16*      dst = (arr ? o2 : o1) + ((size_t)kt * NROWS + row) * 32 + ((s ^ (row & 3)) * 8);
    const float4 a = *(const float4*)src;
    const float4 b = *(const float4*)(src + 4);
    bf16x8 v;
    v[0]=(__bf16)a.x; v[1]=(__bf16)a.y; v[2]=(__bf16)a.z; v[3]=(__bf16)a.w;
    v[4]=(__bf16)b.x; v[5]=(__bf16)b.y; v[6]=(__bf16)b.z; v[7]=(__bf16)b.w;
    *(bf16x8*)dst = v;
  } else {
    // ---- topk: 4 waves/block, one row per wave ----
    const int row = (bid - 2048) * 4 + (tid >> 6);
    const int l   = tid & 63;
    const float* r = feat1 + (size_t)row * CDIM;
    float v[8];
    const float4 a = *(const float4*)(r + l * 8);
    const float4 b = *(const float4*)(r + l * 8 + 4);
    v[0]=a.x; v[1]=a.y; v[2]=a.z; v[3]=a.w;
    v[4]=b.x; v[5]=b.y; v[6]=b.z; v[7]=b.w;

    int sel[TOPK];
#pragma unroll
    for (int s = 0; s < TOPK; ++s) {
      float bv = -__builtin_inff();
      int   bi = 0x7fffffff;
#pragma unroll
      for (int t = 0; t < 8; ++t)
        if (v[t] > bv) { bv = v[t]; bi = l * 8 + t; }   // strict > : smallest idx on tie
#pragma unroll
      for (int off = 32; off > 0; off >>= 1) {
        float ov = __shfl_xor(bv, off);
        int   oi = __shfl_xor(bi, off);
        if (ov > bv || (ov == bv && oi < bi)) { bv = ov; bi = oi; }
      }
      sel[s] = bi;
      const int loc = bi - l * 8;
      if (loc >= 0 && loc < 8) v[loc] = -__builtin_inff();
    }
#define CSWAP(x, y) { int mn = min(sel[x], sel[y]); int mx = max(sel[x], sel[y]); sel[x] = mn; sel[y] = mx; }
    CSWAP(0,1) CSWAP(3,4) CSWAP(2,4) CSWAP(2,3) CSWAP(1,4)
    CSWAP(0,3) CSWAP(0,2) CSWAP(1,3) CSWAP(1,2)
#undef CSWAP
    if (l == 0) {
      keys[row] = (u64)sel[0] | ((u64)sel[1] << 9) | ((u64)sel[2] << 18)
                | ((u64)sel[3] << 27) | ((u64)sel[4] << 36);
    }
  }
}

// ---------------- kernel B: fused GEMM + BCE, 128x256 tile, 2 blocks/CU ----------------
// P[j,i] = dot(prob2[j], prob1[i]). 512 thr = 8 waves (2 j-halves x 4 i-quarters),
// per-wave 64x64 out = acc[4][4]. 3-slot LDS rotation, depth-2 counted-vmcnt pipeline.
__global__ __launch_bounds__(512, 4) void
gemm_loss_kernel(const __bf16* __restrict__ o1k,   // prob1, K-tiled [kt][row][32]
                 const __bf16* __restrict__ o2k,   // prob2, K-tiled
                 const u64* __restrict__ keys,
                 float* __restrict__ partials) {
  __shared__ __bf16 smA[3][BMJ * BK];   // 3 x 8 KB  (prob2 / j)
  __shared__ __bf16 smB[3][BNI * BK];   // 3 x 16 KB (prob1 / i)
  __shared__ float  red[512];

  const int tid = threadIdx.x;
  const int l   = tid & 63, w = tid >> 6;
  const int wr  = w >> 2,  wc = w & 3;     // j-half, i-quarter
  const int lr  = l & 15,  kq = l >> 4;

  // XCD-chunked swizzle: XCD x gets 8 jt x 8 it -> 1MB B + 2MB A < 4MB L2
  const int bid = blockIdx.x;
  const int x   = bid & 7, v = bid >> 3;   // v: 0..63
  const int jt  = (x & 3) * 8 + (v & 7);   // 0..31
  const int it  = (x >> 2) * 8 + (v >> 3); // 0..15
  const int jb  = jt * BMJ, ib = it * BNI;

  f32x4 acc[4][4] = {};

  const __bf16* gA0 = o2k + (size_t)jb * 32;   // + kt*NROWS*32
  const __bf16* gB0 = o1k + (size_t)ib * 32;

  auto stage = [&](int slot, int kt) {
    const size_t ko = (size_t)kt * NROWS * 32;
    // A: 8 KB contiguous, 1 chunk (16B) per thread
    __builtin_amdgcn_global_load_lds(
        (const __attribute__((address_space(1))) unsigned int*)(const void*)(gA0 + ko + tid * 8),
        (__attribute__((address_space(3))) unsigned int*)(void*)&smA[slot][w * 512], 16, 0, 0);
    // B: 16 KB contiguous, 2 chunks per thread
#pragma unroll
    for (int i = 0; i < 2; ++i) {
      __builtin_amdgcn_global_load_lds(
          (const __attribute__((address_space(1))) unsigned int*)(const void*)(gB0 + ko + (i * 512 + tid) * 8),
          (__attribute__((address_space(3))) unsigned int*)(void*)&smB[slot][i * 4096 + w * 512], 16, 0, 0);
    }
  };

  auto compute = [&](int slot) {
    bf16x8 af[4], bfr[4];
#pragma unroll
    for (int m = 0; m < 4; ++m) {
      const int r = wr * 64 + m * 16 + lr;           // 0..127
      const int p = kq ^ (r & 3);
      af[m] = *(const bf16x8*)&smA[slot][r * 32 + p * 8];
    }
#pragma unroll
    for (int n = 0; n < 4; ++n) {
      const int r = wc * 64 + n * 16 + lr;           // 0..255
      const int p = kq ^ (r & 3);
      bfr[n] = *(const bf16x8*)&smB[slot][r * 32 + p * 8];
    }
    __builtin_amdgcn_s_setprio(1);
#pragma unroll
    for (int m = 0; m < 4; ++m)
#pragma unroll
      for (int n = 0; n < 4; ++n)
        acc[m][n] = __builtin_amdgcn_mfma_f32_16x16x32_bf16(af[m], bfr[n], acc[m][n], 0, 0, 0);
    __builtin_amdgcn_s_setprio(0);
  };

  stage(0, 0);
  stage(1, 1);
  for (int kt = 0; kt < NKT; ++kt) {
    if (kt == NKT - 1) asm volatile("s_waitcnt vmcnt(0)" ::: "memory");
    else               asm volatile("s_waitcnt vmcnt(3)" ::: "memory");  // own kt-loads landed
    __builtin_amdgcn_s_barrier();                    // everyone's kt-loads landed
    __builtin_amdgcn_sched_barrier(0);
    if (kt + 2 < NKT) stage((kt + 2) % 3, kt + 2);   // into slot freed last iteration
    compute(kt % 3);
  }

  // ---- epilogue: BCE terms. C/D: col(i) = lane&15, row(j) = (lane>>4)*4 + reg ----
  u64 ki[4];
#pragma unroll
  for (int n = 0; n < 4; ++n)
    ki[n] = keys[ib + wc * 64 + n * 16 + lr];

  float sum = 0.f;
#pragma unroll
  for (int m = 0; m < 4; ++m)
#pragma unroll
    for (int r = 0; r < 4; ++r) {
      const u64 kj = keys[jb + wr * 64 + m * 16 + kq * 4 + r];
#pragma unroll
      for (int n = 0; n < 4; ++n) {
        const float p = acc[m][n][r];
        const bool  t = (kj == ki[n]);
        const float xx = t ? p : (1.0f - p);
        sum += fmaxf(__logf(xx), -100.0f);
      }
    }

  red[tid] = sum;
  __syncthreads();
#pragma unroll
  for (int s = 256; s > 0; s >>= 1) {
    if (tid < s) red[tid] += red[tid + s];
    __syncthreads();
  }
  if (tid == 0) partials[bid] = red[0];
}

// ---------------- kernel C: deterministic finalize ----------------
__global__ void finalize_kernel(const float* __restrict__ partials,
                                float* __restrict__ out) {
  __shared__ float red[256];
  red[threadIdx.x] = partials[threadIdx.x] + partials[threadIdx.x + 256];
  __syncthreads();
  for (int st = 128; st > 0; st >>= 1) {
    if (threadIdx.x < st) red[threadIdx.x] += red[threadIdx.x + st];
    __syncthreads();
  }
  if (threadIdx.x == 0) out[0] = -red[0] * (1.0f / 16777216.0f);
}

extern "C" void kernel_launch(void* const* d_in, const int* in_sizes, int n_in,
                              void* d_out, int out_size, void* d_ws, size_t ws_size,
                              hipStream_t stream) {
  (void)in_sizes; (void)n_in; (void)out_size; (void)ws_size;
  const float* feat1 = (const float*)d_in[0];
  const float* prob1 = (const float*)d_in[2];
  const float* prob2 = (const float*)d_in[3];

  // ws: o1 bf16 (4MB) | o2 bf16 (4MB) | keys (32KB) | partials (2KB)
  __bf16* o1 = (__bf16*)d_ws;
  __bf16* o2 = (__bf16*)((char*)d_ws + (size_t)NROWS * CDIM * 2);
  u64*   keys = (u64*)((char*)d_ws + (size_t)NROWS * CDIM * 4);
  float* partials = (float*)((char*)d_ws + (size_t)NROWS * CDIM * 4 + NROWS * 8);

  prep_kernel<<<3072, 256, 0, stream>>>(prob1, prob2, feat1, o1, o2, keys);
  gemm_loss_kernel<<<512, 512, 0, stream>>>(o1, o2, keys, partials);
  finalize_kernel<<<1, 256, 0, stream>>>(partials, (float*)d_out);
}